// Round 1
// baseline (288.584 us; speedup 1.0000x reference)
//
#include <hip/hip_runtime.h>
#include <math.h>

#define EPSBN 1e-3f

// geometry
#define BB 4
#define TT 4
#define C2 512
#define H2 20
#define W2 20
#define HW2 400
#define RR 4
#define KK 9
#define NS 81
#define NT 3
#define NTS 243
#define TSPAD 256
#define NSPLIT 8
#define CSPL (C2 / NSPLIT) // 64
#define HID 4

// ---------------------------------------------------------------------------
// K_prep: transpose conv2 weights [O][K] -> [K][O]
// ---------------------------------------------------------------------------
__global__ void k_prep(const float* __restrict__ w0, const float* __restrict__ w1,
                       const float* __restrict__ w2,
                       float* __restrict__ wT0, float* __restrict__ wT1,
                       float* __restrict__ wT2) {
    int i = blockIdx.x * 256 + threadIdx.x;
    if (i < 132 * 128) { int c = i >> 7, o = i & 127; wT0[i] = w0[o * 132 + c]; return; }
    i -= 132 * 128;
    if (i < 260 * 256) { int c = i >> 8, o = i & 255; wT1[i] = w1[o * 260 + c]; return; }
    i -= 260 * 256;
    if (i < 516 * 512) { int c = i >> 9, o = i & 511; wT2[i] = w2[o * 516 + c]; }
}

// ---------------------------------------------------------------------------
// K_cost: L1 cost-volume partial sums.
// grid: 4b x 3t x 9dy x 8csplit = 864 blocks, 128 threads (100 active = quads)
// thread: 4 consecutive pixels (one w-quad), sliding 12-float cur window,
// 36 accumulators (9 dx x 4 px). Writes -sum to Spart[cs][b][p][ts].
// ---------------------------------------------------------------------------
__global__ __launch_bounds__(128) void k_cost(const float* __restrict__ f2,
                                              float* __restrict__ Spart) {
    int bi = blockIdx.x;
    int cs = bi & 7;
    int rem = bi >> 3;
    int dy = rem % 9; rem /= 9;
    int t = rem % 3;
    int b = rem / 3;
    int q = threadIdx.x;
    if (q >= 100) return;
    int h = q / 5;
    int w0 = (q % 5) * 4;
    int p = h * W2 + w0;
    int hp = h + dy - RR;
    bool rowOK = (hp >= 0) && (hp < H2);

    const float* cur = f2 + ((size_t)(b * TT + (TT - 1)) * C2) * HW2;
    const float* pst = f2 + ((size_t)(b * TT + t) * C2) * HW2;

    float acc[36];
#pragma unroll
    for (int i = 0; i < 36; ++i) acc[i] = 0.f;

    int c0 = cs * CSPL;
    for (int c = c0; c < c0 + CSPL; ++c) {
        float cv[12];
        if (rowOK) {
            const float* crow = cur + (size_t)c * HW2 + hp * W2;
#pragma unroll
            for (int j = 0; j < 12; ++j) {
                int ww = w0 - 4 + j;
                cv[j] = (ww >= 0 && ww < W2) ? crow[ww] : 0.f;
            }
        } else {
#pragma unroll
            for (int j = 0; j < 12; ++j) cv[j] = 0.f;
        }
        float4 pv = *(const float4*)(pst + (size_t)c * HW2 + p);
        float pvx0 = pv.x, pvx1 = pv.y, pvx2 = pv.z, pvx3 = pv.w;
#pragma unroll
        for (int dx = 0; dx < 9; ++dx) {
            acc[dx * 4 + 0] += fabsf(cv[dx + 0] - pvx0);
            acc[dx * 4 + 1] += fabsf(cv[dx + 1] - pvx1);
            acc[dx * 4 + 2] += fabsf(cv[dx + 2] - pvx2);
            acc[dx * 4 + 3] += fabsf(cv[dx + 3] - pvx3);
        }
    }

    int tsbase = t * NS + dy * KK;
#pragma unroll
    for (int px = 0; px < 4; ++px) {
        float* dst = Spart + ((size_t)(cs * BB + b) * HW2 + (p + px)) * TSPAD + tsbase;
#pragma unroll
        for (int dx = 0; dx < 9; ++dx) dst[dx] = -acc[dx * 4 + px];
    }
}

// ---------------------------------------------------------------------------
// K_smax_conv1: per-pixel: sum 8 partials -> softmax over 81 per t ->
// 1x1 conv 243->4 + BN + SiLU. grid 1600 (b*400+p), 256 threads.
// ---------------------------------------------------------------------------
__global__ __launch_bounds__(256) void k_smax_conv1(
    const float* __restrict__ Spart, const float* __restrict__ w1,
    const float* __restrict__ g1, const float* __restrict__ b1,
    const float* __restrict__ m1, const float* __restrict__ v1,
    float* __restrict__ psim) {
    __shared__ float sS[NTS];
    __shared__ float sP[NTS];
    int bp = blockIdx.x;
    int tid = threadIdx.x;
    if (tid < NTS) {
        float S = 0.f;
#pragma unroll
        for (int k = 0; k < NSPLIT; ++k)
            S += Spart[((size_t)(k * BB * HW2) + bp) * TSPAD + tid];
        sS[tid] = S;
    }
    __syncthreads();
    int wave = tid >> 6, lane = tid & 63;
    if (wave < NT) {
        int base = wave * NS;
        float v0 = sS[base + lane];
        float vo = (lane < NS - 64) ? sS[base + 64 + lane] : -1e30f;
        float m = fmaxf(v0, vo);
#pragma unroll
        for (int off = 32; off; off >>= 1) m = fmaxf(m, __shfl_xor(m, off));
        float e0 = __expf(v0 - m);
        float e1 = (lane < NS - 64) ? __expf(vo - m) : 0.f;
        float s = e0 + e1;
#pragma unroll
        for (int off = 32; off; off >>= 1) s += __shfl_xor(s, off);
        float inv = 1.f / s;
        sP[base + lane] = e0 * inv;
        if (lane < NS - 64) sP[base + 64 + lane] = e1 * inv;
    }
    __syncthreads();
    if (tid < 64) {
        int o = tid >> 4, j = tid & 15;
        float acc = 0.f;
#pragma unroll
        for (int mm = 0; mm < 16; ++mm) {
            int k = j + (mm << 4);
            if (k < NTS) acc += w1[o * NTS + k] * sP[k];
        }
#pragma unroll
        for (int off = 8; off; off >>= 1) acc += __shfl_xor(acc, off);
        if (j == 0) {
            float sc = g1[o] * rsqrtf(v1[o] + EPSBN);
            float y = (acc - m1[o]) * sc + b1[o];
            float sig = 1.f / (1.f + __expf(-y));
            psim[(size_t)bp * HID + o] = y * sig;
        }
    }
}

// ---------------------------------------------------------------------------
// K_resize: bilinear align_corners 20x20 -> 80x80 (pre0) and 40x40 (pre1),
// channels-last [b][p][4].
// ---------------------------------------------------------------------------
__global__ void k_resize(const float* __restrict__ psim, float* __restrict__ pre0,
                         float* __restrict__ pre1) {
    int id = blockIdx.x * 256 + threadIdx.x;
    int Hi, Wi, bb2, pp;
    float* dst;
    if (id < BB * 6400) {
        Hi = 80; Wi = 80; bb2 = id / 6400; pp = id % 6400; dst = pre0 + (size_t)id * 4;
    } else {
        id -= BB * 6400;
        if (id >= BB * 1600) return;
        Hi = 40; Wi = 40; bb2 = id / 1600; pp = id % 1600; dst = pre1 + (size_t)id * 4;
    }
    int yi = pp / Wi, xi = pp % Wi;
    float cy = yi * (19.0f / (Hi - 1));
    float cx = xi * (19.0f / (Wi - 1));
    int y0 = (int)cy; if (y0 > 19) y0 = 19;
    int x0 = (int)cx; if (x0 > 19) x0 = 19;
    int y1 = min(y0 + 1, 19);
    int x1 = min(x0 + 1, 19);
    float wy = cy - y0, wx = cx - x0;
    const float4* base = (const float4*)psim + (size_t)bb2 * HW2;
    float4 v00 = base[y0 * 20 + x0];
    float4 v01 = base[y0 * 20 + x1];
    float4 v10 = base[y1 * 20 + x0];
    float4 v11 = base[y1 * 20 + x1];
    float4 r0, r1, o4;
    r0.x = v00.x * (1.f - wy) + v10.x * wy; r0.y = v00.y * (1.f - wy) + v10.y * wy;
    r0.z = v00.z * (1.f - wy) + v10.z * wy; r0.w = v00.w * (1.f - wy) + v10.w * wy;
    r1.x = v01.x * (1.f - wy) + v11.x * wy; r1.y = v01.y * (1.f - wy) + v11.y * wy;
    r1.z = v01.z * (1.f - wy) + v11.z * wy; r1.w = v01.w * (1.f - wy) + v11.w * wy;
    o4.x = r0.x * (1.f - wx) + r1.x * wx; o4.y = r0.y * (1.f - wx) + r1.y * wx;
    o4.z = r0.z * (1.f - wx) + r1.z * wx; o4.w = r0.w * (1.f - wx) + r1.w * wx;
    *(float4*)dst = o4;
}

// ---------------------------------------------------------------------------
// K_conv2: 1x1 conv (Ci+4 -> Ci=O) + BN + SiLU, fp32.
// Block: 64 pixels x 64 outputs, 256 threads (4 waves x 16 o each).
// x staged in LDS; weights [K][O] read wave-uniform (s_load path).
// ---------------------------------------------------------------------------
template <int O, int K, int HW>
__global__ __launch_bounds__(256) void k_conv2(
    const float* __restrict__ f,   // [B][T][O][HW], uses t = T-1
    const float* __restrict__ pre, // [B][HW][4]
    const float* __restrict__ wT,  // [K][O]
    const float* __restrict__ g, const float* __restrict__ bb,
    const float* __restrict__ mm, const float* __restrict__ vv,
    float* __restrict__ out) {     // [B][O][HW]
    constexpr int Ci = O;
    __shared__ float xs[32][64];
    const int oBlocks = O / 64;
    int ob = blockIdx.x % oBlocks;
    int pb = blockIdx.x / oBlocks;
    int tid = threadIdx.x;
    int lane = tid & 63;
    int wid = tid >> 6;
    int P = pb * 64 + lane;
    int b = P / HW, p = P % HW;
    int o0 = __builtin_amdgcn_readfirstlane(ob * 64 + wid * 16);

    float acc[16];
#pragma unroll
    for (int k = 0; k < 16; ++k) acc[k] = 0.f;

    for (int c0 = 0; c0 < K; c0 += 32) {
        int cmax = min(32, K - c0);
        __syncthreads();
#pragma unroll
        for (int i = 0; i < 8; ++i) {
            int cc = wid + i * 4;
            int c = c0 + cc;
            float val = 0.f;
            if (c < Ci)
                val = f[((size_t)(b * TT + (TT - 1)) * Ci + c) * HW + p];
            else if (c < K)
                val = pre[((size_t)b * HW + p) * 4 + (c - Ci)];
            xs[cc][lane] = val;
        }
        __syncthreads();
        for (int cc = 0; cc < cmax; ++cc) {
            float xv = xs[cc][lane];
            const float* wr = wT + (size_t)(c0 + cc) * O + o0;
#pragma unroll
            for (int u = 0; u < 4; ++u) {
                float4 wq = ((const float4*)wr)[u];
                acc[u * 4 + 0] = fmaf(wq.x, xv, acc[u * 4 + 0]);
                acc[u * 4 + 1] = fmaf(wq.y, xv, acc[u * 4 + 1]);
                acc[u * 4 + 2] = fmaf(wq.z, xv, acc[u * 4 + 2]);
                acc[u * 4 + 3] = fmaf(wq.w, xv, acc[u * 4 + 3]);
            }
        }
    }
#pragma unroll
    for (int k = 0; k < 16; ++k) {
        int o = o0 + k;
        float sc = g[o] * rsqrtf(vv[o] + EPSBN);
        float y = acc[k] * sc + (bb[o] - mm[o] * sc);
        float sig = 1.f / (1.f + __expf(-y));
        out[((size_t)b * O + o) * HW + p] = y * sig;
    }
}

// ---------------------------------------------------------------------------
extern "C" void kernel_launch(void* const* d_in, const int* in_sizes, int n_in,
                              void* d_out, int out_size, void* d_ws, size_t ws_size,
                              hipStream_t stream) {
    const float* f0 = (const float*)d_in[0];
    const float* f1 = (const float*)d_in[1];
    const float* f2 = (const float*)d_in[2];
    // d_in[3], d_in[4]: past/future clip ids (unused by reference)
    const float* w1 = (const float*)d_in[5];
    const float* g1 = (const float*)d_in[6];
    const float* b1 = (const float*)d_in[7];
    const float* m1 = (const float*)d_in[8];
    const float* v1 = (const float*)d_in[9];
    const float* w2_0 = (const float*)d_in[10];
    const float* g2_0 = (const float*)d_in[11];
    const float* b2_0 = (const float*)d_in[12];
    const float* m2_0 = (const float*)d_in[13];
    const float* v2_0 = (const float*)d_in[14];
    const float* w2_1 = (const float*)d_in[15];
    const float* g2_1 = (const float*)d_in[16];
    const float* b2_1 = (const float*)d_in[17];
    const float* m2_1 = (const float*)d_in[18];
    const float* v2_1 = (const float*)d_in[19];
    const float* w2_2 = (const float*)d_in[20];
    const float* g2_2 = (const float*)d_in[21];
    const float* b2_2 = (const float*)d_in[22];
    const float* m2_2 = (const float*)d_in[23];
    const float* v2_2 = (const float*)d_in[24];

    float* ws = (float*)d_ws;
    float* Spart = ws;                    // 8*4*400*256   = 3,276,800
    float* psim = ws + 3276800;           // 4*400*4       = 6,400
    float* pre0 = psim + 6400;            // 4*6400*4      = 102,400
    float* pre1 = pre0 + 102400;          // 4*1600*4      = 25,600
    float* wT0 = pre1 + 25600;            // 132*128       = 16,896
    float* wT1 = wT0 + 16896;             // 260*256       = 66,560
    float* wT2 = wT1 + 66560;             // 516*512       = 264,192
    float* out = (float*)d_out;

    k_prep<<<dim3(1358), dim3(256), 0, stream>>>(w2_0, w2_1, w2_2, wT0, wT1, wT2);
    k_cost<<<dim3(864), dim3(128), 0, stream>>>(f2, Spart);
    k_smax_conv1<<<dim3(1600), dim3(256), 0, stream>>>(Spart, w1, g1, b1, m1, v1, psim);
    k_resize<<<dim3(125), dim3(256), 0, stream>>>(psim, pre0, pre1);
    k_conv2<128, 132, 6400><<<dim3(800), dim3(256), 0, stream>>>(
        f0, pre0, wT0, g2_0, b2_0, m2_0, v2_0, out);
    k_conv2<256, 260, 1600><<<dim3(400), dim3(256), 0, stream>>>(
        f1, pre1, wT1, g2_1, b2_1, m2_1, v2_1, out + 3276800);
    k_conv2<512, 516, 400><<<dim3(200), dim3(256), 0, stream>>>(
        f2, psim, wT2, g2_2, b2_2, m2_2, v2_2, out + 3276800 + 1638400);
}

// Round 3
// 116.850 us; speedup vs baseline: 2.4697x; 2.4697x over previous
//
#include <hip/hip_runtime.h>
#include <math.h>

#define EPSBN 1e-3f

// geometry
#define BB 4
#define TT 4
#define C2 512
#define H2 20
#define W2 20
#define HW2 400
#define RR 4
#define KK 9
#define NS 81
#define NT 3
#define NTS 243
#define TSPAD 256
#define NSPLIT 8
#define CSPL (C2 / NSPLIT) // 64
#define HID 4

typedef __attribute__((ext_vector_type(8))) short short8;
typedef __attribute__((ext_vector_type(4))) float floatx4;

static __device__ inline unsigned short f2bf(float f) {
    unsigned int u = __float_as_uint(f);
    unsigned int r = (u + 0x7fffu + ((u >> 16) & 1u)) >> 16;
    return (unsigned short)r;
}

// ---------------------------------------------------------------------------
// K_prep: conv2 weights -> bf16 [O][KP], BN scale folded in; shift[o]=b-m*sc
// ---------------------------------------------------------------------------
__global__ void k_prep(const float* __restrict__ w0, const float* __restrict__ w1,
                       const float* __restrict__ w2,
                       const float* __restrict__ g0, const float* __restrict__ b0,
                       const float* __restrict__ m0, const float* __restrict__ v0,
                       const float* __restrict__ g1, const float* __restrict__ b1,
                       const float* __restrict__ m1, const float* __restrict__ v1,
                       const float* __restrict__ g2, const float* __restrict__ b2,
                       const float* __restrict__ m2, const float* __restrict__ v2,
                       unsigned short* __restrict__ wb0, unsigned short* __restrict__ wb1,
                       unsigned short* __restrict__ wb2, float* __restrict__ shift) {
    int i = blockIdx.x * 256 + threadIdx.x;
    if (i < 128 * 160) {
        int o = i / 160, k = i % 160;
        float sc = g0[o] * rsqrtf(v0[o] + EPSBN);
        wb0[i] = f2bf(k < 132 ? w0[o * 132 + k] * sc : 0.f);
        return;
    }
    i -= 128 * 160;
    if (i < 256 * 288) {
        int o = i / 288, k = i % 288;
        float sc = g1[o] * rsqrtf(v1[o] + EPSBN);
        wb1[i] = f2bf(k < 260 ? w1[o * 260 + k] * sc : 0.f);
        return;
    }
    i -= 256 * 288;
    if (i < 512 * 544) {
        int o = i / 544, k = i % 544;
        float sc = g2[o] * rsqrtf(v2[o] + EPSBN);
        wb2[i] = f2bf(k < 516 ? w2[o * 516 + k] * sc : 0.f);
        return;
    }
    i -= 512 * 544;
    if (i < 896) {
        if (i < 128) {
            float sc = g0[i] * rsqrtf(v0[i] + EPSBN);
            shift[i] = b0[i] - m0[i] * sc;
        } else if (i < 384) {
            int o = i - 128;
            float sc = g1[o] * rsqrtf(v1[o] + EPSBN);
            shift[i] = b1[o] - m1[o] * sc;
        } else {
            int o = i - 384;
            float sc = g2[o] * rsqrtf(v2[o] + EPSBN);
            shift[i] = b2[o] - m2[o] * sc;
        }
    }
}

// ---------------------------------------------------------------------------
// K_cost: L1 cost-volume partial sums (validated in round 1).
// ---------------------------------------------------------------------------
__global__ __launch_bounds__(128) void k_cost(const float* __restrict__ f2,
                                              float* __restrict__ Spart) {
    int bi = blockIdx.x;
    int cs = bi & 7;
    int rem = bi >> 3;
    int dy = rem % 9; rem /= 9;
    int t = rem % 3;
    int b = rem / 3;
    int q = threadIdx.x;
    if (q >= 100) return;
    int h = q / 5;
    int w0 = (q % 5) * 4;
    int p = h * W2 + w0;
    int hp = h + dy - RR;
    bool rowOK = (hp >= 0) && (hp < H2);

    const float* cur = f2 + ((size_t)(b * TT + (TT - 1)) * C2) * HW2;
    const float* pst = f2 + ((size_t)(b * TT + t) * C2) * HW2;

    float acc[36];
#pragma unroll
    for (int i = 0; i < 36; ++i) acc[i] = 0.f;

    int c0 = cs * CSPL;
    for (int c = c0; c < c0 + CSPL; ++c) {
        float cv[12];
        if (rowOK) {
            const float* crow = cur + (size_t)c * HW2 + hp * W2;
#pragma unroll
            for (int j = 0; j < 12; ++j) {
                int ww = w0 - 4 + j;
                cv[j] = (ww >= 0 && ww < W2) ? crow[ww] : 0.f;
            }
        } else {
#pragma unroll
            for (int j = 0; j < 12; ++j) cv[j] = 0.f;
        }
        float4 pv = *(const float4*)(pst + (size_t)c * HW2 + p);
        float pvx0 = pv.x, pvx1 = pv.y, pvx2 = pv.z, pvx3 = pv.w;
#pragma unroll
        for (int dx = 0; dx < 9; ++dx) {
            acc[dx * 4 + 0] += fabsf(cv[dx + 0] - pvx0);
            acc[dx * 4 + 1] += fabsf(cv[dx + 1] - pvx1);
            acc[dx * 4 + 2] += fabsf(cv[dx + 2] - pvx2);
            acc[dx * 4 + 3] += fabsf(cv[dx + 3] - pvx3);
        }
    }

    int tsbase = t * NS + dy * KK;
#pragma unroll
    for (int px = 0; px < 4; ++px) {
        float* dst = Spart + ((size_t)(cs * BB + b) * HW2 + (p + px)) * TSPAD + tsbase;
#pragma unroll
        for (int dx = 0; dx < 9; ++dx) dst[dx] = -acc[dx * 4 + px];
    }
}

// ---------------------------------------------------------------------------
// K_smax_conv1 (validated in round 1)
// ---------------------------------------------------------------------------
__global__ __launch_bounds__(256) void k_smax_conv1(
    const float* __restrict__ Spart, const float* __restrict__ w1,
    const float* __restrict__ g1, const float* __restrict__ b1,
    const float* __restrict__ m1, const float* __restrict__ v1,
    float* __restrict__ psim) {
    __shared__ float sS[NTS];
    __shared__ float sP[NTS];
    int bp = blockIdx.x;
    int tid = threadIdx.x;
    if (tid < NTS) {
        float S = 0.f;
#pragma unroll
        for (int k = 0; k < NSPLIT; ++k)
            S += Spart[((size_t)(k * BB * HW2) + bp) * TSPAD + tid];
        sS[tid] = S;
    }
    __syncthreads();
    int wave = tid >> 6, lane = tid & 63;
    if (wave < NT) {
        int base = wave * NS;
        float v0 = sS[base + lane];
        float vo = (lane < NS - 64) ? sS[base + 64 + lane] : -1e30f;
        float m = fmaxf(v0, vo);
#pragma unroll
        for (int off = 32; off; off >>= 1) m = fmaxf(m, __shfl_xor(m, off));
        float e0 = __expf(v0 - m);
        float e1 = (lane < NS - 64) ? __expf(vo - m) : 0.f;
        float s = e0 + e1;
#pragma unroll
        for (int off = 32; off; off >>= 1) s += __shfl_xor(s, off);
        float inv = 1.f / s;
        sP[base + lane] = e0 * inv;
        if (lane < NS - 64) sP[base + 64 + lane] = e1 * inv;
    }
    __syncthreads();
    if (tid < 64) {
        int o = tid >> 4, j = tid & 15;
        float acc = 0.f;
#pragma unroll
        for (int mm = 0; mm < 16; ++mm) {
            int k = j + (mm << 4);
            if (k < NTS) acc += w1[o * NTS + k] * sP[k];
        }
#pragma unroll
        for (int off = 8; off; off >>= 1) acc += __shfl_xor(acc, off);
        if (j == 0) {
            float sc = g1[o] * rsqrtf(v1[o] + EPSBN);
            float y = (acc - m1[o]) * sc + b1[o];
            float sig = 1.f / (1.f + __expf(-y));
            psim[(size_t)bp * HID + o] = y * sig;
        }
    }
}

// ---------------------------------------------------------------------------
// K_resize (validated in round 1)
// ---------------------------------------------------------------------------
__global__ void k_resize(const float* __restrict__ psim, float* __restrict__ pre0,
                         float* __restrict__ pre1) {
    int id = blockIdx.x * 256 + threadIdx.x;
    int Hi, Wi, bb2, pp;
    float* dst;
    if (id < BB * 6400) {
        Hi = 80; Wi = 80; bb2 = id / 6400; pp = id % 6400; dst = pre0 + (size_t)id * 4;
    } else {
        id -= BB * 6400;
        if (id >= BB * 1600) return;
        Hi = 40; Wi = 40; bb2 = id / 1600; pp = id % 1600; dst = pre1 + (size_t)id * 4;
    }
    int yi = pp / Wi, xi = pp % Wi;
    float cy = yi * (19.0f / (Hi - 1));
    float cx = xi * (19.0f / (Wi - 1));
    int y0 = (int)cy; if (y0 > 19) y0 = 19;
    int x0 = (int)cx; if (x0 > 19) x0 = 19;
    int y1 = min(y0 + 1, 19);
    int x1 = min(x0 + 1, 19);
    float wy = cy - y0, wx = cx - x0;
    const float4* base = (const float4*)psim + (size_t)bb2 * HW2;
    float4 v00 = base[y0 * 20 + x0];
    float4 v01 = base[y0 * 20 + x1];
    float4 v10 = base[y1 * 20 + x0];
    float4 v11 = base[y1 * 20 + x1];
    float4 r0, r1, o4;
    r0.x = v00.x * (1.f - wy) + v10.x * wy; r0.y = v00.y * (1.f - wy) + v10.y * wy;
    r0.z = v00.z * (1.f - wy) + v10.z * wy; r0.w = v00.w * (1.f - wy) + v10.w * wy;
    r1.x = v01.x * (1.f - wy) + v11.x * wy; r1.y = v01.y * (1.f - wy) + v11.y * wy;
    r1.z = v01.z * (1.f - wy) + v11.z * wy; r1.w = v01.w * (1.f - wy) + v11.w * wy;
    o4.x = r0.x * (1.f - wx) + r1.x * wx; o4.y = r0.y * (1.f - wx) + r1.y * wx;
    o4.z = r0.z * (1.f - wx) + r1.z * wx; o4.w = r0.w * (1.f - wx) + r1.w * wx;
    *(float4*)dst = o4;
}

// ---------------------------------------------------------------------------
// K_gemm: out[b][o][p] = SiLU( sum_c wb[o][c]*x[c][p] + shift[o] )
// x fused on the fly: c<CI from f (last frame, [C][HW] fp32), CI<=c<K from
// pre ([b][HW][4]), zero-pad to KP. LDS-staged [64px][32ch] bf16 per k-step.
// Block: 64o? no — 64px x 64o, 4 waves (2o x 2p), wave = 32o x 32p.
// Pixel tiles never cross batch (TILES per batch), edge tiles guarded.
// ---------------------------------------------------------------------------
#define XLS_STRIDE 40  // shorts; 80B rows -> 16B aligned, bank-spread
template <int O, int KP, int K, int HW, int TILES>
__global__ __launch_bounds__(256) void k_gemm(
    const float* __restrict__ f,   // [B][T][O][HW], uses t=T-1
    const float* __restrict__ pre, // [B][HW][4]
    const unsigned short* __restrict__ wb, // [O][KP] bf16
    const float* __restrict__ shift,
    float* __restrict__ out) {     // [B][O][HW]
    constexpr int CI = O;
    constexpr int OB = O / 64;
    __shared__ unsigned short xls[64 * XLS_STRIDE];

    int tid = threadIdx.x;
    int lane = tid & 63, wv = tid >> 6;
    int ob = blockIdx.x % OB;
    int rest = blockIdx.x / OB;
    int b = rest / TILES;
    int p0 = (rest % TILES) * 64;

    int l15 = lane & 15, lhi = lane >> 4;
    int o_w = ob * 64 + (wv & 1) * 32;
    int pw_loc = (wv >> 1) * 32;

    // staging coords: this thread loads 8 px of one channel row
    int c_l = tid >> 3;        // 0..31
    int pq = (tid & 7) * 8;    // 0..56
    const float* fbase = f + ((size_t)(b * TT + (TT - 1)) * CI) * HW;
    const float* pbase = pre + (size_t)b * HW * 4;

    const short8* aptr0 = (const short8*)(wb + (size_t)(o_w + l15) * KP + lhi * 8);
    const short8* aptr1 = (const short8*)(wb + (size_t)(o_w + 16 + l15) * KP + lhi * 8);

    floatx4 acc00 = {0.f, 0.f, 0.f, 0.f}, acc01 = acc00, acc10 = acc00, acc11 = acc00;

    for (int c0 = 0; c0 < KP; c0 += 32) {
        // ---- stage x[c0..c0+32) for px [p0, p0+64) into LDS (bf16) ----
        __syncthreads();
        {
            int c = c0 + c_l;
            float vals[8];
            if (c < CI) {
                const float* src = fbase + (size_t)c * HW + p0 + pq;
                if (p0 + pq + 7 < HW) {
                    float4 a = ((const float4*)src)[0];
                    float4 bq = ((const float4*)src)[1];
                    vals[0] = a.x; vals[1] = a.y; vals[2] = a.z; vals[3] = a.w;
                    vals[4] = bq.x; vals[5] = bq.y; vals[6] = bq.z; vals[7] = bq.w;
                } else {
#pragma unroll
                    for (int i = 0; i < 8; ++i) {
                        int p = p0 + pq + i;
                        vals[i] = (p < HW) ? src[i] : 0.f;
                    }
                }
            } else if (c < K) {
#pragma unroll
                for (int i = 0; i < 8; ++i) {
                    int p = p0 + pq + i;
                    vals[i] = (p < HW) ? pbase[(size_t)p * 4 + (c - CI)] : 0.f;
                }
            } else {
#pragma unroll
                for (int i = 0; i < 8; ++i) vals[i] = 0.f;
            }
#pragma unroll
            for (int i = 0; i < 8; ++i)
                xls[(pq + i) * XLS_STRIDE + c_l] = f2bf(vals[i]);
        }
        __syncthreads();

        // ---- fragments & MFMA ----
        short8 ca0 = aptr0[c0 >> 3];
        short8 ca1 = aptr1[c0 >> 3];
        short8 cb0 = *(const short8*)&xls[(pw_loc + l15) * XLS_STRIDE + lhi * 8];
        short8 cb1 = *(const short8*)&xls[(pw_loc + 16 + l15) * XLS_STRIDE + lhi * 8];
        acc00 = __builtin_amdgcn_mfma_f32_16x16x32_bf16(ca0, cb0, acc00, 0, 0, 0);
        acc01 = __builtin_amdgcn_mfma_f32_16x16x32_bf16(ca0, cb1, acc01, 0, 0, 0);
        acc10 = __builtin_amdgcn_mfma_f32_16x16x32_bf16(ca1, cb0, acc10, 0, 0, 0);
        acc11 = __builtin_amdgcn_mfma_f32_16x16x32_bf16(ca1, cb1, acc11, 0, 0, 0);
    }

#pragma unroll
    for (int osub = 0; osub < 2; ++osub) {
#pragma unroll
        for (int psub = 0; psub < 2; ++psub) {
            floatx4 d = osub ? (psub ? acc11 : acc10) : (psub ? acc01 : acc00);
            int p = p0 + pw_loc + psub * 16 + l15;
            int obase = o_w + osub * 16 + lhi * 4;
            if (p < HW) {
#pragma unroll
                for (int r = 0; r < 4; ++r) {
                    int o = obase + r;
                    float y = d[r] + shift[o];
                    float sig = 1.f / (1.f + __expf(-y));
                    out[((size_t)b * O + o) * HW + p] = y * sig;
                }
            }
        }
    }
}

// ---------------------------------------------------------------------------
extern "C" void kernel_launch(void* const* d_in, const int* in_sizes, int n_in,
                              void* d_out, int out_size, void* d_ws, size_t ws_size,
                              hipStream_t stream) {
    const float* f0 = (const float*)d_in[0];
    const float* f1 = (const float*)d_in[1];
    const float* f2 = (const float*)d_in[2];
    const float* w1 = (const float*)d_in[5];
    const float* g1 = (const float*)d_in[6];
    const float* b1 = (const float*)d_in[7];
    const float* m1 = (const float*)d_in[8];
    const float* v1 = (const float*)d_in[9];
    const float* w2_0 = (const float*)d_in[10];
    const float* g2_0 = (const float*)d_in[11];
    const float* b2_0 = (const float*)d_in[12];
    const float* m2_0 = (const float*)d_in[13];
    const float* v2_0 = (const float*)d_in[14];
    const float* w2_1 = (const float*)d_in[15];
    const float* g2_1 = (const float*)d_in[16];
    const float* b2_1 = (const float*)d_in[17];
    const float* m2_1 = (const float*)d_in[18];
    const float* v2_1 = (const float*)d_in[19];
    const float* w2_2 = (const float*)d_in[20];
    const float* g2_2 = (const float*)d_in[21];
    const float* b2_2 = (const float*)d_in[22];
    const float* m2_2 = (const float*)d_in[23];
    const float* v2_2 = (const float*)d_in[24];

    float* ws = (float*)d_ws;
    // no aliasing; all regions written-before-read with call-invariant values
    float* Spart = ws;                                   // [0, 3,276,800)
    float* psim = ws + 3276800;                          // 6,400
    float* pre0 = ws + 3283200;                          // 102,400
    float* pre1 = ws + 3385600;                          // 25,600
    unsigned short* wb0 = (unsigned short*)(ws + 3411200);   // 20,480 sh
    unsigned short* wb1 = (unsigned short*)(ws + 3421440);   // 73,728 sh
    unsigned short* wb2 = (unsigned short*)(ws + 3458304);   // 278,528 sh
    float* shift = ws + 3597568;                         // 896 -> end 3,598,464 (14.4 MB)
    float* out = (float*)d_out;

    k_prep<<<dim3(1460), dim3(256), 0, stream>>>(
        w2_0, w2_1, w2_2,
        g2_0, b2_0, m2_0, v2_0,
        g2_1, b2_1, m2_1, v2_1,
        g2_2, b2_2, m2_2, v2_2,
        wb0, wb1, wb2, shift);
    k_cost<<<dim3(864), dim3(128), 0, stream>>>(f2, Spart);
    k_smax_conv1<<<dim3(1600), dim3(256), 0, stream>>>(Spart, w1, g1, b1, m1, v1, psim);
    k_resize<<<dim3(125), dim3(256), 0, stream>>>(psim, pre0, pre1);
    // fused stage+MFMA gemms (no packed-x intermediate)
    k_gemm<128, 160, 132, 6400, 100><<<dim3(800), dim3(256), 0, stream>>>(
        f0, pre0, wb0, shift, out);
    k_gemm<256, 288, 260, 1600, 25><<<dim3(400), dim3(256), 0, stream>>>(
        f1, pre1, wb1, shift + 128, out + 3276800);
    k_gemm<512, 544, 516, 400, 7><<<dim3(224), dim3(256), 0, stream>>>(
        f2, psim, wb2, shift + 384, out + 3276800 + 1638400);
}